// Round 1
// baseline (316.959 us; speedup 1.0000x reference)
//
#include <hip/hip_runtime.h>
#include <math.h>

#define SS 2048
#define BB 64
#define DD 1024

// Kernel A: v[b][d] = sum_e h[b,e] * W[e,d]   (h: [B,D], W: [D,D] row-major [e][d])
// grid: (DD/256, BB/8), block 256. Each thread: one d, 8 b's.
__global__ __launch_bounds__(256) void proj_vec_kernel(
    const float* __restrict__ h, const float* __restrict__ W, float* __restrict__ v) {
    int d  = blockIdx.x * 256 + threadIdx.x;
    int b0 = blockIdx.y * 8;
    float acc[8] = {0.f,0.f,0.f,0.f,0.f,0.f,0.f,0.f};
    for (int e = 0; e < DD; ++e) {
        float w = W[(size_t)e * DD + d];
        #pragma unroll
        for (int j = 0; j < 8; ++j)
            acc[j] = fmaf(h[(b0 + j) * DD + e], w, acc[j]);
    }
    #pragma unroll
    for (int j = 0; j < 8; ++j)
        v[(b0 + j) * DD + d] = acc[j];
}

// Kernel B: energies[b,s] = enc[s,b,:] . v[b,:]
// One wave per row; each wave owns one b and 16 consecutive s values, keeping
// v[b,:] in registers. Grid fixed: 2048 blocks x 256 threads = 8192 waves
// = 64 b * 128 s-chunks * 16 s/chunk = 131072 rows.
__global__ __launch_bounds__(256) void energy_kernel(
    const float* __restrict__ enc, const float* __restrict__ vv, float* __restrict__ e_out) {
    int wid  = (blockIdx.x * 256 + threadIdx.x) >> 6;
    int lane = threadIdx.x & 63;
    int b  = wid & (BB - 1);
    int sc = wid >> 6;            // 0..127
    const float4* vr = (const float4*)(vv + (size_t)b * DD);
    float4 w0 = vr[lane];
    float4 w1 = vr[lane + 64];
    float4 w2 = vr[lane + 128];
    float4 w3 = vr[lane + 192];
    #pragma unroll 1
    for (int i = 0; i < 16; ++i) {
        int s = sc * 16 + i;
        const float4* row = (const float4*)(enc + ((size_t)s * BB + b) * DD);
        float4 a0 = row[lane];
        float4 a1 = row[lane + 64];
        float4 a2 = row[lane + 128];
        float4 a3 = row[lane + 192];
        float acc = a0.x*w0.x + a0.y*w0.y + a0.z*w0.z + a0.w*w0.w
                  + a1.x*w1.x + a1.y*w1.y + a1.z*w1.z + a1.w*w1.w
                  + a2.x*w2.x + a2.y*w2.y + a2.z*w2.z + a2.w*w2.w
                  + a3.x*w3.x + a3.y*w3.y + a3.z*w3.z + a3.w*w3.w;
        #pragma unroll
        for (int off = 32; off; off >>= 1)
            acc += __shfl_xor(acc, off, 64);
        if (lane == 0) e_out[b * SS + s] = acc;
    }
}

// Kernel C: softmax over s per b. 64 blocks x 256 threads, 8 elems/thread.
__global__ __launch_bounds__(256) void softmax_kernel(
    const float* __restrict__ e_in, float* __restrict__ out) {
    int b   = blockIdx.x;
    int tid = threadIdx.x;
    __shared__ float red[256];
    float vals[8];
    float m = -INFINITY;
    #pragma unroll
    for (int k = 0; k < 8; ++k) {
        vals[k] = e_in[b * SS + tid + 256 * k];
        m = fmaxf(m, vals[k]);
    }
    red[tid] = m;
    __syncthreads();
    for (int off = 128; off > 0; off >>= 1) {
        if (tid < off) red[tid] = fmaxf(red[tid], red[tid + off]);
        __syncthreads();
    }
    m = red[0];
    __syncthreads();
    float sum = 0.f;
    #pragma unroll
    for (int k = 0; k < 8; ++k) {
        vals[k] = expf(vals[k] - m);
        sum += vals[k];
    }
    red[tid] = sum;
    __syncthreads();
    for (int off = 128; off > 0; off >>= 1) {
        if (tid < off) red[tid] += red[tid + off];
        __syncthreads();
    }
    float inv = 1.0f / red[0];
    #pragma unroll
    for (int k = 0; k < 8; ++k)
        out[b * SS + tid + 256 * k] = vals[k] * inv;
}

extern "C" void kernel_launch(void* const* d_in, const int* in_sizes, int n_in,
                              void* d_out, int out_size, void* d_ws, size_t ws_size,
                              hipStream_t stream) {
    const float* hidden = (const float*)d_in[0];   // [1,B,D]
    const float* enc    = (const float*)d_in[1];   // [S,B,D]
    const float* W      = (const float*)d_in[2];   // [D,D]
    // d_in[3] = b_attn: constant per-b shift -> cancels in softmax, unused.
    float* out = (float*)d_out;                    // [B,1,S]

    float* v     = (float*)d_ws;                         // B*D floats = 256 KB
    float* e_ws  = (float*)((char*)d_ws + BB * DD * sizeof(float)); // B*S floats = 512 KB

    dim3 gA(DD / 256, BB / 8);
    proj_vec_kernel<<<gA, 256, 0, stream>>>(hidden, W, v);
    energy_kernel<<<2048, 256, 0, stream>>>(enc, v, e_ws);
    softmax_kernel<<<BB, 256, 0, stream>>>(e_ws, out);
}

// Round 2
// 129.646 us; speedup vs baseline: 2.4448x; 2.4448x over previous
//
#include <hip/hip_runtime.h>
#include <math.h>

#define SS 2048
#define BB 64
#define DD 1024

// Kernel A: v[b][d] = sum_e h[b,e] * W[e,d]
// grid (DD/64, BB/4) = (16,16) = 256 blocks, block 256 = 4 waves.
// Thread (eg,dl): eg = e-group (0..3, one per wave), dl = d-lane (0..63).
// Each thread: 4 b's, 256 e iters, unroll 8 -> 8 W loads in flight.
// LDS reduce across the 4 e-groups.
__global__ __launch_bounds__(256) void proj_vec_kernel(
    const float* __restrict__ h, const float* __restrict__ W, float* __restrict__ v) {
    int dl = threadIdx.x & 63;
    int eg = threadIdx.x >> 6;
    int d  = blockIdx.x * 64 + dl;
    int b0 = blockIdx.y * 4;
    int e0 = eg * 256;
    const float* h0 = h + (size_t)(b0 + 0) * DD + e0;
    const float* h1 = h + (size_t)(b0 + 1) * DD + e0;
    const float* h2 = h + (size_t)(b0 + 2) * DD + e0;
    const float* h3 = h + (size_t)(b0 + 3) * DD + e0;
    const float* Wp = W + (size_t)e0 * DD + d;
    float a0 = 0.f, a1 = 0.f, a2 = 0.f, a3 = 0.f;
    #pragma unroll 8
    for (int e = 0; e < 256; ++e) {
        float w = Wp[(size_t)e * DD];     // wave: 64 contiguous floats
        a0 = fmaf(h0[e], w, a0);          // h* are wave-uniform -> scalar loads
        a1 = fmaf(h1[e], w, a1);
        a2 = fmaf(h2[e], w, a2);
        a3 = fmaf(h3[e], w, a3);
    }
    __shared__ float red[4][4][64];
    red[eg][0][dl] = a0; red[eg][1][dl] = a1;
    red[eg][2][dl] = a2; red[eg][3][dl] = a3;
    __syncthreads();
    if (eg == 0) {
        #pragma unroll
        for (int j = 0; j < 4; ++j) {
            float s = red[0][j][dl] + red[1][j][dl] + red[2][j][dl] + red[3][j][dl];
            v[(size_t)(b0 + j) * DD + d] = s;
        }
    }
}

// Kernel B: energies[b,s] = enc[s,b,:] . v[b,:]
// One wave per (b, 16-s chunk); v-row cached in 16 VGPRs; s-rows processed in
// pairs: 8 float4 loads in flight, two independent shfl-reduce chains.
__global__ __launch_bounds__(256) void energy_kernel(
    const float* __restrict__ enc, const float* __restrict__ vv, float* __restrict__ e_out) {
    int wid  = (blockIdx.x * 256 + threadIdx.x) >> 6;
    int lane = threadIdx.x & 63;
    int b  = wid & (BB - 1);
    int sc = wid >> 6;            // 0..127
    const float4* vr = (const float4*)(vv + (size_t)b * DD);
    float4 w0 = vr[lane];
    float4 w1 = vr[lane + 64];
    float4 w2 = vr[lane + 128];
    float4 w3 = vr[lane + 192];
    int s0 = sc * 16;
    #pragma unroll 1
    for (int i = 0; i < 16; i += 2) {
        const float4* r0 = (const float4*)(enc + ((size_t)(s0 + i)     * BB + b) * DD);
        const float4* r1 = (const float4*)(enc + ((size_t)(s0 + i + 1) * BB + b) * DD);
        float4 a0 = r0[lane];
        float4 a1 = r0[lane + 64];
        float4 a2 = r0[lane + 128];
        float4 a3 = r0[lane + 192];
        float4 c0 = r1[lane];
        float4 c1 = r1[lane + 64];
        float4 c2 = r1[lane + 128];
        float4 c3 = r1[lane + 192];
        float p = a0.x*w0.x + a0.y*w0.y + a0.z*w0.z + a0.w*w0.w
                + a1.x*w1.x + a1.y*w1.y + a1.z*w1.z + a1.w*w1.w
                + a2.x*w2.x + a2.y*w2.y + a2.z*w2.z + a2.w*w2.w
                + a3.x*w3.x + a3.y*w3.y + a3.z*w3.z + a3.w*w3.w;
        float q = c0.x*w0.x + c0.y*w0.y + c0.z*w0.z + c0.w*w0.w
                + c1.x*w1.x + c1.y*w1.y + c1.z*w1.z + c1.w*w1.w
                + c2.x*w2.x + c2.y*w2.y + c2.z*w2.z + c2.w*w2.w
                + c3.x*w3.x + c3.y*w3.y + c3.z*w3.z + c3.w*w3.w;
        #pragma unroll
        for (int off = 32; off; off >>= 1) {
            p += __shfl_xor(p, off, 64);
            q += __shfl_xor(q, off, 64);
        }
        if (lane == 0) {
            e_out[b * SS + s0 + i]     = p;
            e_out[b * SS + s0 + i + 1] = q;
        }
    }
}

// Kernel C: softmax over s per b. 64 blocks x 256 threads, 8 elems/thread.
__global__ __launch_bounds__(256) void softmax_kernel(
    const float* __restrict__ e_in, float* __restrict__ out) {
    int b   = blockIdx.x;
    int tid = threadIdx.x;
    __shared__ float red[256];
    float vals[8];
    float m = -INFINITY;
    #pragma unroll
    for (int k = 0; k < 8; ++k) {
        vals[k] = e_in[b * SS + tid + 256 * k];
        m = fmaxf(m, vals[k]);
    }
    red[tid] = m;
    __syncthreads();
    for (int off = 128; off > 0; off >>= 1) {
        if (tid < off) red[tid] = fmaxf(red[tid], red[tid + off]);
        __syncthreads();
    }
    m = red[0];
    __syncthreads();
    float sum = 0.f;
    #pragma unroll
    for (int k = 0; k < 8; ++k) {
        vals[k] = expf(vals[k] - m);
        sum += vals[k];
    }
    red[tid] = sum;
    __syncthreads();
    for (int off = 128; off > 0; off >>= 1) {
        if (tid < off) red[tid] += red[tid + off];
        __syncthreads();
    }
    float inv = 1.0f / red[0];
    #pragma unroll
    for (int k = 0; k < 8; ++k)
        out[b * SS + tid + 256 * k] = vals[k] * inv;
}

extern "C" void kernel_launch(void* const* d_in, const int* in_sizes, int n_in,
                              void* d_out, int out_size, void* d_ws, size_t ws_size,
                              hipStream_t stream) {
    const float* hidden = (const float*)d_in[0];   // [1,B,D]
    const float* enc    = (const float*)d_in[1];   // [S,B,D]
    const float* W      = (const float*)d_in[2];   // [D,D]
    // d_in[3] = b_attn: constant per-b shift -> cancels in softmax, unused.
    float* out = (float*)d_out;                    // [B,1,S]

    float* v    = (float*)d_ws;                                      // B*D = 256 KB
    float* e_ws = (float*)((char*)d_ws + BB * DD * sizeof(float));   // B*S = 512 KB

    dim3 gA(DD / 64, BB / 4);
    proj_vec_kernel<<<gA, 256, 0, stream>>>(hidden, W, v);
    energy_kernel<<<2048, 256, 0, stream>>>(enc, v, e_ws);
    softmax_kernel<<<BB, 256, 0, stream>>>(e_ws, out);
}

// Round 3
// 114.472 us; speedup vs baseline: 2.7689x; 1.1326x over previous
//
#include <hip/hip_runtime.h>
#include <math.h>

#define SS 2048
#define BB 64
#define DD 1024

// Kernel A: v[b][d] = sum_e h[b,e] * W[e,d]
// grid (DD/64, BB/4) = (16,16), block 512 = 8 waves (e-split 8).
// Thread (eg,dl): eg = e-group (0..7, one per wave, 128 e iters), dl = d-lane.
// Each thread accumulates 4 b's; LDS reduce across the 8 e-groups.
__global__ __launch_bounds__(512) void proj_vec_kernel(
    const float* __restrict__ h, const float* __restrict__ W, float* __restrict__ v) {
    int dl = threadIdx.x & 63;
    int eg = threadIdx.x >> 6;
    int d  = blockIdx.x * 64 + dl;
    int b0 = blockIdx.y * 4;
    int e0 = eg * 128;
    const float* h0 = h + (size_t)(b0 + 0) * DD + e0;
    const float* h1 = h + (size_t)(b0 + 1) * DD + e0;
    const float* h2 = h + (size_t)(b0 + 2) * DD + e0;
    const float* h3 = h + (size_t)(b0 + 3) * DD + e0;
    const float* Wp = W + (size_t)e0 * DD + d;
    float a0 = 0.f, a1 = 0.f, a2 = 0.f, a3 = 0.f;
    #pragma unroll 8
    for (int e = 0; e < 128; ++e) {
        float w = Wp[(size_t)e * DD];     // wave: 64 contiguous floats
        a0 = fmaf(h0[e], w, a0);          // h* wave-uniform -> scalar loads
        a1 = fmaf(h1[e], w, a1);
        a2 = fmaf(h2[e], w, a2);
        a3 = fmaf(h3[e], w, a3);
    }
    __shared__ float red[8][4][64];
    red[eg][0][dl] = a0; red[eg][1][dl] = a1;
    red[eg][2][dl] = a2; red[eg][3][dl] = a3;
    __syncthreads();
    if (eg < 4) {   // wave eg reduces b0+eg
        float s = 0.f;
        #pragma unroll
        for (int g = 0; g < 8; ++g) s += red[g][eg][dl];
        v[(size_t)(b0 + eg) * DD + d] = s;
    }
}

// Kernel B: energies[b,s] = enc[s,b,:] . v[b,:]
// One wave per (b, 16-s chunk); v-row in 16 VGPRs. Main loop has NO cross-lane
// reduce: per-lane partials go to LDS; epilogue reduces 16 rows at once.
__global__ __launch_bounds__(256) void energy_kernel(
    const float* __restrict__ enc, const float* __restrict__ vv, float* __restrict__ e_out) {
    __shared__ float part[4][16][65];    // [wave][row][lane], +1 pad -> 2-way max
    int tid  = threadIdx.x;
    int w    = tid >> 6;
    int lane = tid & 63;
    int wid  = blockIdx.x * 4 + w;
    int b  = wid & (BB - 1);
    int sc = wid >> 6;                   // 0..127
    const float4* vr = (const float4*)(vv + (size_t)b * DD);
    float4 w0 = vr[lane];
    float4 w1 = vr[lane + 64];
    float4 w2 = vr[lane + 128];
    float4 w3 = vr[lane + 192];
    int s0 = sc * 16;
    #pragma unroll 2
    for (int i = 0; i < 16; ++i) {
        const float4* r0 = (const float4*)(enc + ((size_t)(s0 + i) * BB + b) * DD);
        float4 a0 = r0[lane];
        float4 a1 = r0[lane + 64];
        float4 a2 = r0[lane + 128];
        float4 a3 = r0[lane + 192];
        float p = a0.x*w0.x + a0.y*w0.y + a0.z*w0.z + a0.w*w0.w
                + a1.x*w1.x + a1.y*w1.y + a1.z*w1.z + a1.w*w1.w
                + a2.x*w2.x + a2.y*w2.y + a2.z*w2.z + a2.w*w2.w
                + a3.x*w3.x + a3.y*w3.y + a3.z*w3.z + a3.w*w3.w;
        part[w][i][lane] = p;
    }
    __syncthreads();
    // Epilogue: 4 lanes per row; each sums 16 LDS entries, then 2 shfls.
    int r  = lane >> 2;                  // row 0..15
    int qd = lane & 3;                   // quarter
    float sum = 0.f;
    #pragma unroll
    for (int k = 0; k < 16; ++k) sum += part[w][r][qd * 16 + k];
    sum += __shfl_xor(sum, 1, 64);
    sum += __shfl_xor(sum, 2, 64);
    if (qd == 0) e_out[b * SS + s0 + r] = sum;
}

// Kernel C: softmax over s per b. 64 blocks x 256 threads, 8 elems/thread.
__global__ __launch_bounds__(256) void softmax_kernel(
    const float* __restrict__ e_in, float* __restrict__ out) {
    int b   = blockIdx.x;
    int tid = threadIdx.x;
    __shared__ float red[256];
    float vals[8];
    float m = -INFINITY;
    #pragma unroll
    for (int k = 0; k < 8; ++k) {
        vals[k] = e_in[b * SS + tid + 256 * k];
        m = fmaxf(m, vals[k]);
    }
    red[tid] = m;
    __syncthreads();
    for (int off = 128; off > 0; off >>= 1) {
        if (tid < off) red[tid] = fmaxf(red[tid], red[tid + off]);
        __syncthreads();
    }
    m = red[0];
    __syncthreads();
    float sum = 0.f;
    #pragma unroll
    for (int k = 0; k < 8; ++k) {
        vals[k] = expf(vals[k] - m);
        sum += vals[k];
    }
    red[tid] = sum;
    __syncthreads();
    for (int off = 128; off > 0; off >>= 1) {
        if (tid < off) red[tid] += red[tid + off];
        __syncthreads();
    }
    float inv = 1.0f / red[0];
    #pragma unroll
    for (int k = 0; k < 8; ++k)
        out[b * SS + tid + 256 * k] = vals[k] * inv;
}

extern "C" void kernel_launch(void* const* d_in, const int* in_sizes, int n_in,
                              void* d_out, int out_size, void* d_ws, size_t ws_size,
                              hipStream_t stream) {
    const float* hidden = (const float*)d_in[0];   // [1,B,D]
    const float* enc    = (const float*)d_in[1];   // [S,B,D]
    const float* W      = (const float*)d_in[2];   // [D,D]
    // d_in[3] = b_attn: constant per-b shift -> cancels in softmax, unused.
    float* out = (float*)d_out;                    // [B,1,S]

    float* v    = (float*)d_ws;                                      // B*D = 256 KB
    float* e_ws = (float*)((char*)d_ws + BB * DD * sizeof(float));   // B*S = 512 KB

    dim3 gA(DD / 64, BB / 4);
    proj_vec_kernel<<<gA, 512, 0, stream>>>(hidden, W, v);
    energy_kernel<<<2048, 256, 0, stream>>>(enc, v, e_ws);
    softmax_kernel<<<BB, 256, 0, stream>>>(e_ws, out);
}